// Round 9
// baseline (211.852 us; speedup 1.0000x reference)
//
#include <hip/hip_runtime.h>
#include <math.h>

#define N_NODES 100000
#define N_EDGES 1600000
#define NF 16        // node features
#define HID 32
#define OUTD 12
#define CIN3 48      // x | T_o | T_i

// Geometry: measured-best compromise (r7). p3 run length = CHUNK/NB = 6.1
// records per (block,bucket) (write-combining), p4 grid = 2*NB = 2048 blocks
// (8/CU, full wave occupancy). Do not change one without the other.
#define NB   1024                // buckets per direction
#define RNG  98                  // nodes per bucket: 1024*98 = 100352 >= 100000
#define PBLK 256                 // partition blocks
#define CHUNK ((N_EDGES + PBLK - 1) / PBLK)   // 6250
#define CAP   2560               // records per LDS sort chunk (10 per thread)
#define CAPT  10                 // CAP / 256
#define ACCN  7                  // ceil(RNG/16)

typedef unsigned int uint;

// ============================================================================
// MAIN PATH. Records split into two 4B streams (r9):
//   recX  = other | (local << 20)        — consumed by p4 (gather)
//   recLW = (local << 25) | wfix24       — consumed by kdeg (degree)
// No f32 LDS atomics anywhere (slow RMW path on CDNA4, measured r6->r7);
// kdeg uses native u32 atomics on 2^24 fixed-point weights.
// ============================================================================

// ---- P1: per-block bucket histograms (LDS counters) ----
__global__ __launch_bounds__(256)
void p1_count(const int* __restrict__ ei, uint* __restrict__ cntD, uint* __restrict__ cntS) {
    __shared__ uint cD[NB], cS[NB];
    int t = threadIdx.x, blk = blockIdx.x;
    for (int i = t; i < NB; i += 256) { cD[i] = 0; cS[i] = 0; }
    __syncthreads();
    int lo = blk * CHUNK, hi = min(lo + CHUNK, N_EDGES);
    for (int e = lo + t; e < hi; e += 256) {
        uint s = (uint)ei[e];
        uint d = (uint)ei[N_EDGES + e];
        atomicAdd(&cS[s / RNG], 1u);
        atomicAdd(&cD[d / RNG], 1u);
    }
    __syncthreads();
    for (int i = t; i < NB; i += 256) {
        cntD[i * PBLK + blk] = cD[i];
        cntS[i * PBLK + blk] = cS[i];
    }
}

// ---- P2a: bucket totals (row sums over blocks); grid 2*NB ----
__global__ __launch_bounds__(256)
void p2a_rowsum(const uint* __restrict__ cntD, const uint* __restrict__ cntS,
                uint* __restrict__ totD, uint* __restrict__ totS) {
    __shared__ uint red[256];
    int t = threadIdx.x;
    bool isS = blockIdx.x >= NB;
    int b = isS ? (blockIdx.x - NB) : blockIdx.x;
    const uint* cnt = isS ? cntS : cntD;
    red[t] = cnt[b * PBLK + t];
    __syncthreads();
    for (int s = 128; s > 0; s >>= 1) { if (t < s) red[t] += red[t + s]; __syncthreads(); }
    if (t == 0) (isS ? totS : totD)[b] = red[0];
}

// ---- P2b: exclusive scan of bucket totals -> baseD/baseS (NB+1 each) ----
__global__ __launch_bounds__(256)
void p2b_scan(const uint* __restrict__ totD, const uint* __restrict__ totS,
              uint* __restrict__ baseD, uint* __restrict__ baseS) {
    __shared__ uint part[256];
    int t = threadIdx.x;
    for (int dir = 0; dir < 2; ++dir) {
        const uint* tot = dir ? totS : totD;
        uint* base = dir ? baseS : baseD;
        uint v[4]; uint s = 0;
#pragma unroll
        for (int k = 0; k < 4; ++k) { v[k] = tot[t * 4 + k]; s += v[k]; }
        part[t] = s;
        __syncthreads();
        if (t == 0) {
            uint a = 0;
            for (int k = 0; k < 256; ++k) { uint x = part[k]; part[k] = a; a += x; }
            base[NB] = a;
        }
        __syncthreads();
        uint a = part[t];
#pragma unroll
        for (int k = 0; k < 4; ++k) { base[t * 4 + k] = a; a += v[k]; }
        __syncthreads();
    }
}

// ---- P2c: per-bucket exclusive scan across partition blocks + base; grid 2*NB ----
__global__ __launch_bounds__(256)
void p2c_rowscan(const uint* __restrict__ cntD, const uint* __restrict__ cntS,
                 const uint* __restrict__ baseD, const uint* __restrict__ baseS,
                 uint* __restrict__ offD, uint* __restrict__ offS) {
    __shared__ uint row[PBLK];
    int t = threadIdx.x;
    bool isS = blockIdx.x >= NB;
    int b = isS ? (blockIdx.x - NB) : blockIdx.x;
    const uint* cnt = isS ? cntS : cntD;
    const uint* base = isS ? baseS : baseD;
    uint* off = isS ? offS : offD;
    row[t] = cnt[b * PBLK + t];
    __syncthreads();
    if (t == 0) {
        uint a = base[b];
        for (int k = 0; k < PBLK; ++k) { uint v = row[k]; row[k] = a; a += v; }
    }
    __syncthreads();
    off[b * PBLK + t] = row[t];
}

// ---- P3: reorder edges into bucket-contiguous split records (plain stores) ----
__global__ __launch_bounds__(256)
void p3_scatter(const int* __restrict__ ei, const float* __restrict__ ew,
                const uint* __restrict__ offD, const uint* __restrict__ offS,
                uint* __restrict__ recXD, uint* __restrict__ recWD,
                uint* __restrict__ recXS, uint* __restrict__ recWS) {
    __shared__ uint curD[NB], curS[NB];
    int t = threadIdx.x, blk = blockIdx.x;
    for (int b = t; b < NB; b += 256) {
        curD[b] = offD[b * PBLK + blk];
        curS[b] = offS[b * PBLK + blk];
    }
    __syncthreads();
    int lo = blk * CHUNK, hi = min(lo + CHUNK, N_EDGES);
    for (int e = lo + t; e < hi; e += 256) {
        uint s = (uint)ei[e];
        uint d = (uint)ei[N_EDGES + e];
        float w = ew[e];
        uint wfix = (uint)(w * 16777216.0f + 0.5f);   // 2^24 fixed point, w in [0.05,1)
        uint bd = d / RNG, dl = d - bd * RNG;
        uint p = atomicAdd(&curD[bd], 1u);            // u32 LDS atomic (native)
        recXD[p] = s | (dl << 20);
        recWD[p] = (dl << 25) | wfix;
        uint bs = s / RNG, sl = s - bs * RNG;
        uint p2 = atomicAdd(&curS[bs], 1u);
        recXS[p2] = d | (sl << 20);
        recWS[p2] = (sl << 25) | wfix;
    }
}

// ---- KDEG: per-bucket weighted degree via u32 fixed-point LDS atomics ----
// S-binned -> deg_out -> inv_out ; D-binned -> deg_in -> inv_in. grid 2*NB.
__global__ __launch_bounds__(256)
void kdeg(const uint* __restrict__ recWD, const uint* __restrict__ recWS,
          const uint* __restrict__ baseD, const uint* __restrict__ baseS,
          float* __restrict__ inv_in, float* __restrict__ inv_out) {
    __shared__ uint dacc[RNG];
    int t = threadIdx.x;
    bool isS = blockIdx.x >= NB;
    int b = isS ? (blockIdx.x - NB) : blockIdx.x;
    const uint* rec = isS ? recWS : recWD;
    const uint* base = isS ? baseS : baseD;
    float* inv = isS ? inv_out : inv_in;
    for (int i = t; i < RNG; i += 256) dacc[i] = 0u;
    __syncthreads();
    uint lo = base[b], hi = base[b + 1];
    for (uint e = lo + t; e < hi; e += 256) {
        uint r = rec[e];
        atomicAdd(&dacc[r >> 25], r & 0x1FFFFFFu);    // native u32 LDS atomic
    }
    __syncthreads();
    int n0 = b * RNG;
    for (int i = t; i < RNG; i += 256) {
        int n = n0 + i;
        if (n < N_NODES) inv[n] = 16777216.0f / (float)dacc[i];  // inf for isolated: never gathered
    }
}

// ---- P4: counting-sort bucket records by local node, register-accumulate ----
// thread (slot s = t>>4, feature f = t&15); slot s owns local nodes s, s+16, ...
__global__ __launch_bounds__(256)
void p4_sorted(const uint* __restrict__ recXD, const uint* __restrict__ recXS,
               const uint* __restrict__ baseD, const uint* __restrict__ baseS,
               const float* __restrict__ x,
               const float* __restrict__ inv_out, const float* __restrict__ inv_in,
               float* __restrict__ To, float* __restrict__ Ti) {
    __shared__ uint sorted[CAP];          // 10 KiB
    __shared__ uint scnt[RNG];
    __shared__ uint cstart[RNG + 1];
    __shared__ uint scur[RNG];
    __shared__ uint sscan[256];
    int t = threadIdx.x;
    bool isS = blockIdx.x >= NB;
    int b = isS ? (blockIdx.x - NB) : blockIdx.x;
    const uint* rec = isS ? recXS : recXD;
    const uint* base = isS ? baseS : baseD;
    const float* inv = isS ? inv_in : inv_out;
    float* out = isS ? Ti : To;

    int f = t & 15, s = t >> 4;
    uint lo = base[b], hi = base[b + 1];

    float acc[ACCN];
#pragma unroll
    for (int k = 0; k < ACCN; ++k) acc[k] = 0.0f;

    for (uint chunk = lo; chunk < hi; chunk += CAP) {
        uint n_in = min(hi - chunk, (uint)CAP);
        for (int i = t; i < RNG; i += 256) scnt[i] = 0;
        __syncthreads();
        // pass A: stream records (4B each), count by local node, stash in regs
        uint stash[CAPT];
#pragma unroll
        for (int k = 0; k < CAPT; ++k) {
            uint i = (uint)(k * 256 + t);
            if (i < n_in) {
                uint r = rec[chunk + i];
                stash[k] = r;
                atomicAdd(&scnt[r >> 20], 1u);    // u32 LDS atomic (native)
            }
        }
        __syncthreads();
        // parallel exclusive scan of scnt (Hillis-Steele over 256 lanes)
        uint v = (t < RNG) ? scnt[t] : 0u;
        sscan[t] = v;
        __syncthreads();
#pragma unroll
        for (int d = 1; d < 256; d <<= 1) {
            uint a = (t >= d) ? sscan[t - d] : 0u;
            __syncthreads();
            sscan[t] += a;
            __syncthreads();
        }
        if (t < RNG) { cstart[t] = sscan[t] - v; scur[t] = sscan[t] - v; }
        if (t == 0) cstart[RNG] = sscan[RNG - 1];
        __syncthreads();
        // pass B: place into sorted order
#pragma unroll
        for (int k = 0; k < CAPT; ++k) {
            uint i = (uint)(k * 256 + t);
            if (i < n_in) {
                uint r = stash[k];
                uint p = atomicAdd(&scur[r >> 20], 1u);
                sorted[p] = r;
            }
        }
        __syncthreads();
        // accumulate: slot s walks its nodes' contiguous edge lists
#pragma unroll
        for (int k = 0; k < ACCN; ++k) {
            int n = s + 16 * k;
            if (n < RNG) {
                uint j = cstart[n], j1 = cstart[n + 1];
                for (; j + 8 <= j1; j += 8) {
                    uint p0 = sorted[j],     p1 = sorted[j + 1], p2 = sorted[j + 2], p3 = sorted[j + 3];
                    uint p4 = sorted[j + 4], p5 = sorted[j + 5], p6 = sorted[j + 6], p7 = sorted[j + 7];
                    uint o0 = p0 & 0xFFFFFu, o1 = p1 & 0xFFFFFu, o2 = p2 & 0xFFFFFu, o3 = p3 & 0xFFFFFu;
                    uint o4 = p4 & 0xFFFFFu, o5 = p5 & 0xFFFFFu, o6 = p6 & 0xFFFFFu, o7 = p7 & 0xFFFFFu;
                    float g0 = x[(size_t)o0 * NF + f], g1 = x[(size_t)o1 * NF + f];
                    float g2 = x[(size_t)o2 * NF + f], g3 = x[(size_t)o3 * NF + f];
                    float g4 = x[(size_t)o4 * NF + f], g5 = x[(size_t)o5 * NF + f];
                    float g6 = x[(size_t)o6 * NF + f], g7 = x[(size_t)o7 * NF + f];
                    float w0 = inv[o0], w1 = inv[o1], w2 = inv[o2], w3 = inv[o3];
                    float w4 = inv[o4], w5 = inv[o5], w6 = inv[o6], w7 = inv[o7];
                    acc[k] += g0 * w0 + g1 * w1 + g2 * w2 + g3 * w3
                            + g4 * w4 + g5 * w5 + g6 * w6 + g7 * w7;
                }
                for (; j < j1; ++j) {
                    uint p = sorted[j];
                    uint o = p & 0xFFFFFu;
                    acc[k] += x[(size_t)o * NF + f] * inv[o];
                }
            }
        }
        __syncthreads();   // before next chunk overwrites LDS
    }

    // write out: each (node, f) exactly once, coalesced
#pragma unroll
    for (int k = 0; k < ACCN; ++k) {
        int n = s + 16 * k;
        if (n < RNG) {
            size_t g = (size_t)b * RNG + n;
            if (g < N_NODES) out[g * NF + f] = acc[k];
        }
    }
}

// ---- combine + TRANSPOSE weights: WT[h][c] ----
__global__ void wprep_kernel(const float* __restrict__ Wz, const float* __restrict__ Wh,
                             float* __restrict__ WzT, float* __restrict__ WhT) {
    int t = blockIdx.x * blockDim.x + threadIdx.x;
    if (t >= 2 * CIN3 * HID) return;
    const float* W = (t < CIN3 * HID) ? Wz : Wh;
    float* WT      = (t < CIN3 * HID) ? WzT : WhT;
    int i = (t < CIN3 * HID) ? t : (t - CIN3 * HID);
    int c = i / HID;
    int h = i - c * HID;
    float v;
    if (c < 16)      v = W[(0 * 48 + c) * 32 + h] + W[(2 * 48 + c) * 32 + h];
    else if (c < 32) v = W[(1 * 48 + (c - 16)) * 32 + h];
    else             v = W[(3 * 48 + (c - 32)) * 32 + h];
    WT[h * CIN3 + c] = v;
}

// ---- per-node fused GRU-collapse + output ----
__global__ __launch_bounds__(256)
void node_kernel(const float* __restrict__ x, const float* __restrict__ To,
                 const float* __restrict__ Ti,
                 const float* __restrict__ WzT, const float* __restrict__ WhT,
                 const float* __restrict__ bz, const float* __restrict__ bh,
                 const float* __restrict__ linW, const float* __restrict__ linb,
                 float* __restrict__ out) {
    __shared__ __align__(16) float sWz[HID * CIN3];
    __shared__ __align__(16) float sWh[HID * CIN3];
    __shared__ __align__(16) float sBz[HID], sBh[HID];
    __shared__ __align__(16) float sLW[HID * OUTD];
    __shared__ __align__(16) float sLb[OUTD];

    for (int i = threadIdx.x; i < HID * CIN3; i += 256) { sWz[i] = WzT[i]; sWh[i] = WhT[i]; }
    if (threadIdx.x < HID) { sBz[threadIdx.x] = bz[threadIdx.x]; sBh[threadIdx.x] = bh[threadIdx.x]; }
    for (int i = threadIdx.x; i < HID * OUTD; i += 256) sLW[i] = linW[i];
    if (threadIdx.x < OUTD) sLb[threadIdx.x] = linb[threadIdx.x];
    __syncthreads();

    int n = blockIdx.x * 256 + threadIdx.x;
    if (n >= N_NODES) return;

    float feat[CIN3];
#pragma unroll
    for (int q = 0; q < 4; ++q) {
        float4 v = ((const float4*)(x + (size_t)n * NF))[q];
        feat[q*4+0]=v.x; feat[q*4+1]=v.y; feat[q*4+2]=v.z; feat[q*4+3]=v.w;
    }
#pragma unroll
    for (int q = 0; q < 4; ++q) {
        float4 v = ((const float4*)(To + (size_t)n * NF))[q];
        feat[16+q*4+0]=v.x; feat[16+q*4+1]=v.y; feat[16+q*4+2]=v.z; feat[16+q*4+3]=v.w;
    }
#pragma unroll
    for (int q = 0; q < 4; ++q) {
        float4 v = ((const float4*)(Ti + (size_t)n * NF))[q];
        feat[32+q*4+0]=v.x; feat[32+q*4+1]=v.y; feat[32+q*4+2]=v.z; feat[32+q*4+3]=v.w;
    }

    float o[OUTD];
#pragma unroll
    for (int j = 0; j < OUTD; ++j) o[j] = sLb[j];

#pragma unroll 2
    for (int h = 0; h < HID; ++h) {
        float az = sBz[h];
        float ah = sBh[h];
        const float4* wz4 = (const float4*)(sWz + h * CIN3);
        const float4* wh4 = (const float4*)(sWh + h * CIN3);
#pragma unroll
        for (int q = 0; q < CIN3 / 4; ++q) {
            float4 wz = wz4[q];
            float4 wh = wh4[q];
            float f0 = feat[q*4+0], f1 = feat[q*4+1], f2 = feat[q*4+2], f3 = feat[q*4+3];
            az += f0*wz.x + f1*wz.y + f2*wz.z + f3*wz.w;
            ah += f0*wh.x + f1*wh.y + f2*wh.z + f3*wh.w;
        }
        float z  = 1.0f / (1.0f + expf(-az));
        float ht = tanhf(ah);
        float r  = fmaxf((1.0f - z) * ht, 0.0f);
#pragma unroll
        for (int j = 0; j < OUTD; ++j) o[j] += r * sLW[h * OUTD + j];
    }

    float4* op = (float4*)(out + (size_t)n * OUTD);
    op[0] = make_float4(o[0], o[1], o[2],  o[3]);
    op[1] = make_float4(o[4], o[5], o[6],  o[7]);
    op[2] = make_float4(o[8], o[9], o[10], o[11]);
}

// ============================================================================
// FALLBACK (ws too small): compact atomic path (round-2 structure)
// ============================================================================
__global__ void zero_kernel(float* __restrict__ p, int n) {
    int i = blockIdx.x * blockDim.x + threadIdx.x;
    int stride = gridDim.x * blockDim.x;
    for (; i < n; i += stride) p[i] = 0.0f;
}
__global__ void degree_compact(const int* __restrict__ ei, const float* __restrict__ ew,
                               float* __restrict__ deg_out, float* __restrict__ deg_in) {
    int e = blockIdx.x * blockDim.x + threadIdx.x;
    if (e >= N_EDGES) return;
    atomicAdd(&deg_out[ei[e]], ew[e]);
    atomicAdd(&deg_in[ei[N_EDGES + e]], ew[e]);
}
__global__ void rcp_compact(float* __restrict__ a, float* __restrict__ b) {
    int n = blockIdx.x * blockDim.x + threadIdx.x;
    if (n >= N_NODES) return;
    a[n] = 1.0f / a[n]; b[n] = 1.0f / b[n];
}
__global__ __launch_bounds__(256)
void scatter_kernel(const int* __restrict__ ei, const float* __restrict__ x,
                    const float* __restrict__ inv_out, const float* __restrict__ inv_in,
                    float* __restrict__ To, float* __restrict__ Ti) {
    int t = blockIdx.x * blockDim.x + threadIdx.x;
    if (t >= N_EDGES * NF) return;
    int e = t >> 4, f = t & 15;
    int src = ei[e], dst = ei[N_EDGES + e];
    atomicAdd(&To[dst * NF + f], x[src * NF + f] * inv_out[src]);
    atomicAdd(&Ti[src * NF + f], x[dst * NF + f] * inv_in[dst]);
}

// ============================================================================
extern "C" void kernel_launch(void* const* d_in, const int* in_sizes, int n_in,
                              void* d_out, int out_size, void* d_ws, size_t ws_size,
                              hipStream_t stream) {
    const float* x    = (const float*)d_in[0];
    const int*   ei   = (const int*)  d_in[1];
    const float* ew   = (const float*)d_in[2];
    const float* Wz   = (const float*)d_in[3];
    const float* bz   = (const float*)d_in[4];
    // d_in[5], d_in[6] (W_r, b_r) dead: H0 == 0 makes the reset gate unused.
    const float* Wh   = (const float*)d_in[7];
    const float* bh   = (const float*)d_in[8];
    const float* linW = (const float*)d_in[9];
    const float* linb = (const float*)d_in[10];

    float* ws = (float*)d_ws;

    // ---- main-path workspace layout (dwords) ----
    size_t off = 0;
    uint* recXD = (uint*)(ws + off);  off += (size_t)N_EDGES;
    uint* recWD = (uint*)(ws + off);  off += (size_t)N_EDGES;
    uint* recXS = (uint*)(ws + off);  off += (size_t)N_EDGES;
    uint* recWS = (uint*)(ws + off);  off += (size_t)N_EDGES;
    uint* cntD  = (uint*)(ws + off);  off += (size_t)NB * PBLK;
    uint* cntS  = (uint*)(ws + off);  off += (size_t)NB * PBLK;
    uint* offD  = (uint*)(ws + off);  off += (size_t)NB * PBLK;
    uint* offS  = (uint*)(ws + off);  off += (size_t)NB * PBLK;
    uint* totD  = (uint*)(ws + off);  off += NB;
    uint* totS  = (uint*)(ws + off);  off += NB;
    uint* baseD = (uint*)(ws + off);  off += NB + 1;
    uint* baseS = (uint*)(ws + off);  off += NB + 1;
    float* inv_out = ws + off;        off += N_NODES;
    float* inv_in  = ws + off;        off += N_NODES;
    float* To   = ws + off;           off += (size_t)NF * N_NODES;
    float* Ti   = ws + off;           off += (size_t)NF * N_NODES;
    float* WzT  = ws + off;           off += CIN3 * HID;
    float* WhT  = ws + off;           off += CIN3 * HID;
    size_t need = off * sizeof(float);

    if (ws_size >= need) {
        p1_count    <<<PBLK,  256, 0, stream>>>(ei, cntD, cntS);
        p2a_rowsum  <<<2*NB,  256, 0, stream>>>(cntD, cntS, totD, totS);
        p2b_scan    <<<1,     256, 0, stream>>>(totD, totS, baseD, baseS);
        p2c_rowscan <<<2*NB,  256, 0, stream>>>(cntD, cntS, baseD, baseS, offD, offS);
        p3_scatter  <<<PBLK,  256, 0, stream>>>(ei, ew, offD, offS, recXD, recWD, recXS, recWS);
        kdeg        <<<2*NB,  256, 0, stream>>>(recWD, recWS, baseD, baseS, inv_in, inv_out);
        wprep_kernel<<<12,    256, 0, stream>>>(Wz, Wh, WzT, WhT);
        p4_sorted   <<<2*NB,  256, 0, stream>>>(recXD, recXS, baseD, baseS, x, inv_out, inv_in, To, Ti);
        node_kernel <<<(N_NODES + 255) / 256, 256, 0, stream>>>(x, To, Ti, WzT, WhT, bz, bh,
                                                                linW, linb, (float*)d_out);
    } else {
        float* fTo  = ws;
        float* fTi  = ws + 16 * N_NODES;
        float* fIo  = ws + 32 * N_NODES;
        float* fIi  = ws + 33 * N_NODES;
        float* fWzT = ws + 34 * N_NODES;
        float* fWhT = fWzT + CIN3 * HID;
        zero_kernel<<<2048, 256, 0, stream>>>(fTo, 34 * N_NODES);
        degree_compact<<<(N_EDGES + 255) / 256, 256, 0, stream>>>(ei, ew, fIo, fIi);
        rcp_compact<<<(N_NODES + 255) / 256, 256, 0, stream>>>(fIo, fIi);
        scatter_kernel<<<(N_EDGES * NF + 255) / 256, 256, 0, stream>>>(ei, x, fIo, fIi, fTo, fTi);
        wprep_kernel<<<12, 256, 0, stream>>>(Wz, Wh, fWzT, fWhT);
        node_kernel<<<(N_NODES + 255) / 256, 256, 0, stream>>>(x, fTo, fTi, fWzT, fWhT, bz, bh,
                                                               linW, linb, (float*)d_out);
    }
}

// Round 10
// 174.756 us; speedup vs baseline: 1.2123x; 1.2123x over previous
//
#include <hip/hip_runtime.h>
#include <math.h>

#define N_NODES 100000
#define N_EDGES 1600000
#define NF 16        // node features
#define HID 32
#define OUTD 12
#define CIN3 48      // x | T_o | T_i

// Geometry: measured-best (r7). p3 run length = CHUNK/NB = 6.1 records per
// (block,bucket) -> 48B per touched line with ONE uint2 stream per direction
// (r9 showed 4x4B streams double write amplification: 89->175MB). p4 grid =
// 2*NB = 2048 blocks (8/CU). Do not change one without the other.
#define NB   1024                // buckets per direction
#define RNG  98                  // nodes per bucket: 1024*98 = 100352 >= 100000
#define PBLK 256                 // partition blocks
#define CHUNK ((N_EDGES + PBLK - 1) / PBLK)   // 6250
#define CAP   3328               // records per LDS sort chunk (13 per thread)
#define CAPT  13                 // CAP / 256
#define ACCN  7                  // ceil(RNG/16)

typedef unsigned int uint;

// ============================================================================
// MAIN PATH. One uint2 record stream per direction:
//   .x = other | (local << 20)       — consumed by p4 (gather)
//   .y = (local << 25) | wfix24      — consumed by kdeg (degree, u32 atomics)
// No f32 LDS atomics anywhere (slow RMW path on CDNA4, measured r6->r7).
// ============================================================================

// ---- P1: per-block bucket histograms (LDS counters) ----
__global__ __launch_bounds__(256)
void p1_count(const int* __restrict__ ei, uint* __restrict__ cntD, uint* __restrict__ cntS) {
    __shared__ uint cD[NB], cS[NB];
    int t = threadIdx.x, blk = blockIdx.x;
    for (int i = t; i < NB; i += 256) { cD[i] = 0; cS[i] = 0; }
    __syncthreads();
    int lo = blk * CHUNK, hi = min(lo + CHUNK, N_EDGES);
    for (int e = lo + t; e < hi; e += 256) {
        uint s = (uint)ei[e];
        uint d = (uint)ei[N_EDGES + e];
        atomicAdd(&cS[s / RNG], 1u);
        atomicAdd(&cD[d / RNG], 1u);
    }
    __syncthreads();
    for (int i = t; i < NB; i += 256) {
        cntD[i * PBLK + blk] = cD[i];
        cntS[i * PBLK + blk] = cS[i];
    }
}

// ---- P2a: bucket totals (row sums over blocks); grid 2*NB ----
__global__ __launch_bounds__(256)
void p2a_rowsum(const uint* __restrict__ cntD, const uint* __restrict__ cntS,
                uint* __restrict__ totD, uint* __restrict__ totS) {
    __shared__ uint red[256];
    int t = threadIdx.x;
    bool isS = blockIdx.x >= NB;
    int b = isS ? (blockIdx.x - NB) : blockIdx.x;
    const uint* cnt = isS ? cntS : cntD;
    red[t] = cnt[b * PBLK + t];
    __syncthreads();
    for (int s = 128; s > 0; s >>= 1) { if (t < s) red[t] += red[t + s]; __syncthreads(); }
    if (t == 0) (isS ? totS : totD)[b] = red[0];
}

// ---- P2b: exclusive scan of bucket totals -> baseD/baseS (NB+1 each) ----
__global__ __launch_bounds__(256)
void p2b_scan(const uint* __restrict__ totD, const uint* __restrict__ totS,
              uint* __restrict__ baseD, uint* __restrict__ baseS) {
    __shared__ uint part[256];
    int t = threadIdx.x;
    for (int dir = 0; dir < 2; ++dir) {
        const uint* tot = dir ? totS : totD;
        uint* base = dir ? baseS : baseD;
        uint v[4]; uint s = 0;
#pragma unroll
        for (int k = 0; k < 4; ++k) { v[k] = tot[t * 4 + k]; s += v[k]; }
        part[t] = s;
        __syncthreads();
        if (t == 0) {
            uint a = 0;
            for (int k = 0; k < 256; ++k) { uint x = part[k]; part[k] = a; a += x; }
            base[NB] = a;
        }
        __syncthreads();
        uint a = part[t];
#pragma unroll
        for (int k = 0; k < 4; ++k) { base[t * 4 + k] = a; a += v[k]; }
        __syncthreads();
    }
}

// ---- P2c: per-bucket exclusive scan across partition blocks + base; grid 2*NB ----
__global__ __launch_bounds__(256)
void p2c_rowscan(const uint* __restrict__ cntD, const uint* __restrict__ cntS,
                 const uint* __restrict__ baseD, const uint* __restrict__ baseS,
                 uint* __restrict__ offD, uint* __restrict__ offS) {
    __shared__ uint row[PBLK];
    int t = threadIdx.x;
    bool isS = blockIdx.x >= NB;
    int b = isS ? (blockIdx.x - NB) : blockIdx.x;
    const uint* cnt = isS ? cntS : cntD;
    const uint* base = isS ? baseS : baseD;
    uint* off = isS ? offS : offD;
    row[t] = cnt[b * PBLK + t];
    __syncthreads();
    if (t == 0) {
        uint a = base[b];
        for (int k = 0; k < PBLK; ++k) { uint v = row[k]; row[k] = a; a += v; }
    }
    __syncthreads();
    off[b * PBLK + t] = row[t];
}

// ---- P3: reorder edges into bucket-contiguous uint2 records (plain stores) ----
__global__ __launch_bounds__(256)
void p3_scatter(const int* __restrict__ ei, const float* __restrict__ ew,
                const uint* __restrict__ offD, const uint* __restrict__ offS,
                uint2* __restrict__ recD, uint2* __restrict__ recS) {
    __shared__ uint curD[NB], curS[NB];
    int t = threadIdx.x, blk = blockIdx.x;
    for (int b = t; b < NB; b += 256) {
        curD[b] = offD[b * PBLK + blk];
        curS[b] = offS[b * PBLK + blk];
    }
    __syncthreads();
    int lo = blk * CHUNK, hi = min(lo + CHUNK, N_EDGES);
    for (int e = lo + t; e < hi; e += 256) {
        uint s = (uint)ei[e];
        uint d = (uint)ei[N_EDGES + e];
        uint wfix = (uint)(ew[e] * 16777216.0f + 0.5f);   // 2^24 fixed point
        uint bd = d / RNG, dl = d - bd * RNG;
        uint p = atomicAdd(&curD[bd], 1u);                // u32 LDS atomic (native)
        recD[p] = make_uint2(s | (dl << 20), (dl << 25) | wfix);
        uint bs = s / RNG, sl = s - bs * RNG;
        uint p2 = atomicAdd(&curS[bs], 1u);
        recS[p2] = make_uint2(d | (sl << 20), (sl << 25) | wfix);
    }
}

// ---- KDEG: per-bucket weighted degree via u32 fixed-point LDS atomics ----
// D-binned (own=dst) -> deg_in -> inv_in ; S-binned (own=src) -> deg_out -> inv_out
__global__ __launch_bounds__(256)
void kdeg(const uint2* __restrict__ recD, const uint2* __restrict__ recS,
          const uint* __restrict__ baseD, const uint* __restrict__ baseS,
          float* __restrict__ inv_in, float* __restrict__ inv_out) {
    __shared__ uint dacc[RNG];
    int t = threadIdx.x;
    bool isS = blockIdx.x >= NB;
    int b = isS ? (blockIdx.x - NB) : blockIdx.x;
    const uint2* rec = isS ? recS : recD;
    const uint* base = isS ? baseS : baseD;
    float* inv = isS ? inv_out : inv_in;
    for (int i = t; i < RNG; i += 256) dacc[i] = 0u;
    __syncthreads();
    uint lo = base[b], hi = base[b + 1];
    for (uint e = lo + t; e < hi; e += 256) {
        uint ry = rec[e].y;
        atomicAdd(&dacc[ry >> 25], ry & 0x1FFFFFFu);      // native u32 LDS atomic
    }
    __syncthreads();
    int n0 = b * RNG;
    for (int i = t; i < RNG; i += 256) {
        int n = n0 + i;
        if (n < N_NODES) inv[n] = 16777216.0f / (float)dacc[i];  // inf for isolated: never gathered
    }
}

// ---- P4: counting-sort bucket records by local node, register-accumulate ----
// thread (slot s = t>>4, feature f = t&15); slot s owns local nodes s, s+16, ...
__global__ __launch_bounds__(256)
void p4_sorted(const uint2* __restrict__ recD, const uint2* __restrict__ recS,
               const uint* __restrict__ baseD, const uint* __restrict__ baseS,
               const float* __restrict__ x,
               const float* __restrict__ inv_out, const float* __restrict__ inv_in,
               float* __restrict__ To, float* __restrict__ Ti) {
    __shared__ uint sorted[CAP];          // 13 KiB
    __shared__ uint scnt[RNG];
    __shared__ uint cstart[RNG + 1];
    __shared__ uint scur[RNG];
    __shared__ uint sscan[256];
    int t = threadIdx.x;
    bool isS = blockIdx.x >= NB;
    int b = isS ? (blockIdx.x - NB) : blockIdx.x;
    const uint2* rec = isS ? recS : recD;
    const uint* base = isS ? baseS : baseD;
    const float* inv = isS ? inv_in : inv_out;
    float* out = isS ? Ti : To;

    int f = t & 15, s = t >> 4;
    uint lo = base[b], hi = base[b + 1];

    float acc[ACCN];
#pragma unroll
    for (int k = 0; k < ACCN; ++k) acc[k] = 0.0f;

    for (uint chunk = lo; chunk < hi; chunk += CAP) {
        uint n_in = min(hi - chunk, (uint)CAP);
        for (int i = t; i < RNG; i += 256) scnt[i] = 0;
        __syncthreads();
        // pass A: stream records, count by local node, stash .x in regs
        uint stash[CAPT];
#pragma unroll
        for (int k = 0; k < CAPT; ++k) {
            uint i = (uint)(k * 256 + t);
            if (i < n_in) {
                uint r = rec[chunk + i].x;
                stash[k] = r;
                atomicAdd(&scnt[r >> 20], 1u);    // u32 LDS atomic (native)
            }
        }
        __syncthreads();
        // parallel exclusive scan of scnt (Hillis-Steele over 256 lanes)
        uint v = (t < RNG) ? scnt[t] : 0u;
        sscan[t] = v;
        __syncthreads();
#pragma unroll
        for (int d = 1; d < 256; d <<= 1) {
            uint a = (t >= d) ? sscan[t - d] : 0u;
            __syncthreads();
            sscan[t] += a;
            __syncthreads();
        }
        if (t < RNG) { cstart[t] = sscan[t] - v; scur[t] = sscan[t] - v; }
        if (t == 0) cstart[RNG] = sscan[RNG - 1];
        __syncthreads();
        // pass B: place into sorted order
#pragma unroll
        for (int k = 0; k < CAPT; ++k) {
            uint i = (uint)(k * 256 + t);
            if (i < n_in) {
                uint r = stash[k];
                uint p = atomicAdd(&scur[r >> 20], 1u);
                sorted[p] = r;
            }
        }
        __syncthreads();
        // accumulate: slot s walks its nodes' contiguous edge lists
#pragma unroll
        for (int k = 0; k < ACCN; ++k) {
            int n = s + 16 * k;
            if (n < RNG) {
                uint j = cstart[n], j1 = cstart[n + 1];
                for (; j + 8 <= j1; j += 8) {
                    uint p0 = sorted[j],     p1 = sorted[j + 1], p2 = sorted[j + 2], p3 = sorted[j + 3];
                    uint p4 = sorted[j + 4], p5 = sorted[j + 5], p6 = sorted[j + 6], p7 = sorted[j + 7];
                    uint o0 = p0 & 0xFFFFFu, o1 = p1 & 0xFFFFFu, o2 = p2 & 0xFFFFFu, o3 = p3 & 0xFFFFFu;
                    uint o4 = p4 & 0xFFFFFu, o5 = p5 & 0xFFFFFu, o6 = p6 & 0xFFFFFu, o7 = p7 & 0xFFFFFu;
                    float g0 = x[(size_t)o0 * NF + f], g1 = x[(size_t)o1 * NF + f];
                    float g2 = x[(size_t)o2 * NF + f], g3 = x[(size_t)o3 * NF + f];
                    float g4 = x[(size_t)o4 * NF + f], g5 = x[(size_t)o5 * NF + f];
                    float g6 = x[(size_t)o6 * NF + f], g7 = x[(size_t)o7 * NF + f];
                    float w0 = inv[o0], w1 = inv[o1], w2 = inv[o2], w3 = inv[o3];
                    float w4 = inv[o4], w5 = inv[o5], w6 = inv[o6], w7 = inv[o7];
                    acc[k] += g0 * w0 + g1 * w1 + g2 * w2 + g3 * w3
                            + g4 * w4 + g5 * w5 + g6 * w6 + g7 * w7;
                }
                for (; j < j1; ++j) {
                    uint p = sorted[j];
                    uint o = p & 0xFFFFFu;
                    acc[k] += x[(size_t)o * NF + f] * inv[o];
                }
            }
        }
        __syncthreads();   // before next chunk overwrites LDS
    }

    // write out: each (node, f) exactly once, coalesced
#pragma unroll
    for (int k = 0; k < ACCN; ++k) {
        int n = s + 16 * k;
        if (n < RNG) {
            size_t g = (size_t)b * RNG + n;
            if (g < N_NODES) out[g * NF + f] = acc[k];
        }
    }
}

// ---- combine + TRANSPOSE weights: WT[h][c] ----
__global__ void wprep_kernel(const float* __restrict__ Wz, const float* __restrict__ Wh,
                             float* __restrict__ WzT, float* __restrict__ WhT) {
    int t = blockIdx.x * blockDim.x + threadIdx.x;
    if (t >= 2 * CIN3 * HID) return;
    const float* W = (t < CIN3 * HID) ? Wz : Wh;
    float* WT      = (t < CIN3 * HID) ? WzT : WhT;
    int i = (t < CIN3 * HID) ? t : (t - CIN3 * HID);
    int c = i / HID;
    int h = i - c * HID;
    float v;
    if (c < 16)      v = W[(0 * 48 + c) * 32 + h] + W[(2 * 48 + c) * 32 + h];
    else if (c < 32) v = W[(1 * 48 + (c - 16)) * 32 + h];
    else             v = W[(3 * 48 + (c - 32)) * 32 + h];
    WT[h * CIN3 + c] = v;
}

// ---- per-node fused GRU-collapse + output ----
__global__ __launch_bounds__(256)
void node_kernel(const float* __restrict__ x, const float* __restrict__ To,
                 const float* __restrict__ Ti,
                 const float* __restrict__ WzT, const float* __restrict__ WhT,
                 const float* __restrict__ bz, const float* __restrict__ bh,
                 const float* __restrict__ linW, const float* __restrict__ linb,
                 float* __restrict__ out) {
    __shared__ __align__(16) float sWz[HID * CIN3];
    __shared__ __align__(16) float sWh[HID * CIN3];
    __shared__ __align__(16) float sBz[HID], sBh[HID];
    __shared__ __align__(16) float sLW[HID * OUTD];
    __shared__ __align__(16) float sLb[OUTD];

    for (int i = threadIdx.x; i < HID * CIN3; i += 256) { sWz[i] = WzT[i]; sWh[i] = WhT[i]; }
    if (threadIdx.x < HID) { sBz[threadIdx.x] = bz[threadIdx.x]; sBh[threadIdx.x] = bh[threadIdx.x]; }
    for (int i = threadIdx.x; i < HID * OUTD; i += 256) sLW[i] = linW[i];
    if (threadIdx.x < OUTD) sLb[threadIdx.x] = linb[threadIdx.x];
    __syncthreads();

    int n = blockIdx.x * 256 + threadIdx.x;
    if (n >= N_NODES) return;

    float feat[CIN3];
#pragma unroll
    for (int q = 0; q < 4; ++q) {
        float4 v = ((const float4*)(x + (size_t)n * NF))[q];
        feat[q*4+0]=v.x; feat[q*4+1]=v.y; feat[q*4+2]=v.z; feat[q*4+3]=v.w;
    }
#pragma unroll
    for (int q = 0; q < 4; ++q) {
        float4 v = ((const float4*)(To + (size_t)n * NF))[q];
        feat[16+q*4+0]=v.x; feat[16+q*4+1]=v.y; feat[16+q*4+2]=v.z; feat[16+q*4+3]=v.w;
    }
#pragma unroll
    for (int q = 0; q < 4; ++q) {
        float4 v = ((const float4*)(Ti + (size_t)n * NF))[q];
        feat[32+q*4+0]=v.x; feat[32+q*4+1]=v.y; feat[32+q*4+2]=v.z; feat[32+q*4+3]=v.w;
    }

    float o[OUTD];
#pragma unroll
    for (int j = 0; j < OUTD; ++j) o[j] = sLb[j];

#pragma unroll 2
    for (int h = 0; h < HID; ++h) {
        float az = sBz[h];
        float ah = sBh[h];
        const float4* wz4 = (const float4*)(sWz + h * CIN3);
        const float4* wh4 = (const float4*)(sWh + h * CIN3);
#pragma unroll
        for (int q = 0; q < CIN3 / 4; ++q) {
            float4 wz = wz4[q];
            float4 wh = wh4[q];
            float f0 = feat[q*4+0], f1 = feat[q*4+1], f2 = feat[q*4+2], f3 = feat[q*4+3];
            az += f0*wz.x + f1*wz.y + f2*wz.z + f3*wz.w;
            ah += f0*wh.x + f1*wh.y + f2*wh.z + f3*wh.w;
        }
        float z  = 1.0f / (1.0f + expf(-az));
        float ht = tanhf(ah);
        float r  = fmaxf((1.0f - z) * ht, 0.0f);
#pragma unroll
        for (int j = 0; j < OUTD; ++j) o[j] += r * sLW[h * OUTD + j];
    }

    float4* op = (float4*)(out + (size_t)n * OUTD);
    op[0] = make_float4(o[0], o[1], o[2],  o[3]);
    op[1] = make_float4(o[4], o[5], o[6],  o[7]);
    op[2] = make_float4(o[8], o[9], o[10], o[11]);
}

// ============================================================================
// FALLBACK (ws too small): compact atomic path (round-2 structure)
// ============================================================================
__global__ void zero_kernel(float* __restrict__ p, int n) {
    int i = blockIdx.x * blockDim.x + threadIdx.x;
    int stride = gridDim.x * blockDim.x;
    for (; i < n; i += stride) p[i] = 0.0f;
}
__global__ void degree_compact(const int* __restrict__ ei, const float* __restrict__ ew,
                               float* __restrict__ deg_out, float* __restrict__ deg_in) {
    int e = blockIdx.x * blockDim.x + threadIdx.x;
    if (e >= N_EDGES) return;
    atomicAdd(&deg_out[ei[e]], ew[e]);
    atomicAdd(&deg_in[ei[N_EDGES + e]], ew[e]);
}
__global__ void rcp_compact(float* __restrict__ a, float* __restrict__ b) {
    int n = blockIdx.x * blockDim.x + threadIdx.x;
    if (n >= N_NODES) return;
    a[n] = 1.0f / a[n]; b[n] = 1.0f / b[n];
}
__global__ __launch_bounds__(256)
void scatter_kernel(const int* __restrict__ ei, const float* __restrict__ x,
                    const float* __restrict__ inv_out, const float* __restrict__ inv_in,
                    float* __restrict__ To, float* __restrict__ Ti) {
    int t = blockIdx.x * blockDim.x + threadIdx.x;
    if (t >= N_EDGES * NF) return;
    int e = t >> 4, f = t & 15;
    int src = ei[e], dst = ei[N_EDGES + e];
    atomicAdd(&To[dst * NF + f], x[src * NF + f] * inv_out[src]);
    atomicAdd(&Ti[src * NF + f], x[dst * NF + f] * inv_in[dst]);
}

// ============================================================================
extern "C" void kernel_launch(void* const* d_in, const int* in_sizes, int n_in,
                              void* d_out, int out_size, void* d_ws, size_t ws_size,
                              hipStream_t stream) {
    const float* x    = (const float*)d_in[0];
    const int*   ei   = (const int*)  d_in[1];
    const float* ew   = (const float*)d_in[2];
    const float* Wz   = (const float*)d_in[3];
    const float* bz   = (const float*)d_in[4];
    // d_in[5], d_in[6] (W_r, b_r) dead: H0 == 0 makes the reset gate unused.
    const float* Wh   = (const float*)d_in[7];
    const float* bh   = (const float*)d_in[8];
    const float* linW = (const float*)d_in[9];
    const float* linb = (const float*)d_in[10];

    float* ws = (float*)d_ws;

    // ---- main-path workspace layout (dwords) ----
    size_t off = 0;
    uint2* recD = (uint2*)(ws + off); off += 2 * (size_t)N_EDGES;
    uint2* recS = (uint2*)(ws + off); off += 2 * (size_t)N_EDGES;
    uint* cntD  = (uint*)(ws + off);  off += (size_t)NB * PBLK;
    uint* cntS  = (uint*)(ws + off);  off += (size_t)NB * PBLK;
    uint* offD  = (uint*)(ws + off);  off += (size_t)NB * PBLK;
    uint* offS  = (uint*)(ws + off);  off += (size_t)NB * PBLK;
    uint* totD  = (uint*)(ws + off);  off += NB;
    uint* totS  = (uint*)(ws + off);  off += NB;
    uint* baseD = (uint*)(ws + off);  off += NB + 1;
    uint* baseS = (uint*)(ws + off);  off += NB + 1;
    float* inv_out = ws + off;        off += N_NODES;
    float* inv_in  = ws + off;        off += N_NODES;
    float* To   = ws + off;           off += (size_t)NF * N_NODES;
    float* Ti   = ws + off;           off += (size_t)NF * N_NODES;
    float* WzT  = ws + off;           off += CIN3 * HID;
    float* WhT  = ws + off;           off += CIN3 * HID;
    size_t need = off * sizeof(float);

    if (ws_size >= need) {
        p1_count    <<<PBLK,  256, 0, stream>>>(ei, cntD, cntS);
        p2a_rowsum  <<<2*NB,  256, 0, stream>>>(cntD, cntS, totD, totS);
        p2b_scan    <<<1,     256, 0, stream>>>(totD, totS, baseD, baseS);
        p2c_rowscan <<<2*NB,  256, 0, stream>>>(cntD, cntS, baseD, baseS, offD, offS);
        p3_scatter  <<<PBLK,  256, 0, stream>>>(ei, ew, offD, offS, recD, recS);
        kdeg        <<<2*NB,  256, 0, stream>>>(recD, recS, baseD, baseS, inv_in, inv_out);
        wprep_kernel<<<12,    256, 0, stream>>>(Wz, Wh, WzT, WhT);
        p4_sorted   <<<2*NB,  256, 0, stream>>>(recD, recS, baseD, baseS, x, inv_out, inv_in, To, Ti);
        node_kernel <<<(N_NODES + 255) / 256, 256, 0, stream>>>(x, To, Ti, WzT, WhT, bz, bh,
                                                                linW, linb, (float*)d_out);
    } else {
        float* fTo  = ws;
        float* fTi  = ws + 16 * N_NODES;
        float* fIo  = ws + 32 * N_NODES;
        float* fIi  = ws + 33 * N_NODES;
        float* fWzT = ws + 34 * N_NODES;
        float* fWhT = fWzT + CIN3 * HID;
        zero_kernel<<<2048, 256, 0, stream>>>(fTo, 34 * N_NODES);
        degree_compact<<<(N_EDGES + 255) / 256, 256, 0, stream>>>(ei, ew, fIo, fIi);
        rcp_compact<<<(N_NODES + 255) / 256, 256, 0, stream>>>(fIo, fIi);
        scatter_kernel<<<(N_EDGES * NF + 255) / 256, 256, 0, stream>>>(ei, x, fIo, fIi, fTo, fTi);
        wprep_kernel<<<12, 256, 0, stream>>>(Wz, Wh, fWzT, fWhT);
        node_kernel<<<(N_NODES + 255) / 256, 256, 0, stream>>>(x, fTo, fTi, fWzT, fWhT, bz, bh,
                                                               linW, linb, (float*)d_out);
    }
}

// Round 11
// 155.953 us; speedup vs baseline: 1.3584x; 1.1206x over previous
//
#include <hip/hip_runtime.h>
#include <math.h>

#define N_NODES 100000
#define N_EDGES 1600000
#define NF 16        // node features
#define HID 32
#define OUTD 12
#define CIN3 48      // x | T_o | T_i

// Geometry: measured-best (r7). p3 run length = CHUNK/NB = 6.1 records per
// (block,bucket) -> 48B per touched line with ONE uint2 stream per direction
// (r9: 4x4B streams doubled write amplification, 89->175MB). p4 grid = 2*NB =
// 2048 blocks (8/CU). p1/p3 use 1024-thread blocks (r11): 4x wave concurrency
// at unchanged store layout. Do not change NB/PBLK independently.
#define NB   1024                // buckets per direction
#define RNG  98                  // nodes per bucket: 1024*98 = 100352 >= 100000
#define PBLK 256                 // partition blocks
#define PT   1024                // partition threads per block
#define CHUNK ((N_EDGES + PBLK - 1) / PBLK)   // 6250
#define CAP   2560               // records per LDS sort chunk (r7-proven)
#define CAPT  10                 // CAP / 256
#define ACCN  7                  // ceil(RNG/16)

typedef unsigned int uint;

// ============================================================================
// MAIN PATH. One uint2 record stream per direction:
//   .x = other | (local << 20)       — consumed by p4 (gather)
//   .y = (local << 25) | wfix24      — consumed by kdeg (degree, u32 atomics)
// No f32 LDS atomics anywhere (slow RMW path on CDNA4, measured r6->r7).
// ============================================================================

// ---- P1: per-block bucket histograms (LDS counters); 1024 threads ----
__global__ __launch_bounds__(PT)
void p1_count(const int* __restrict__ ei, uint* __restrict__ cntD, uint* __restrict__ cntS) {
    __shared__ uint cD[NB], cS[NB];
    int t = threadIdx.x, blk = blockIdx.x;
    for (int i = t; i < NB; i += PT) { cD[i] = 0; cS[i] = 0; }
    __syncthreads();
    int lo = blk * CHUNK, hi = min(lo + CHUNK, N_EDGES);
    for (int e = lo + t; e < hi; e += PT) {
        uint s = (uint)ei[e];
        uint d = (uint)ei[N_EDGES + e];
        atomicAdd(&cS[s / RNG], 1u);
        atomicAdd(&cD[d / RNG], 1u);
    }
    __syncthreads();
    for (int i = t; i < NB; i += PT) {
        cntD[i * PBLK + blk] = cD[i];
        cntS[i * PBLK + blk] = cS[i];
    }
}

// ---- P2a: bucket totals (row sums over blocks); grid 2*NB ----
__global__ __launch_bounds__(256)
void p2a_rowsum(const uint* __restrict__ cntD, const uint* __restrict__ cntS,
                uint* __restrict__ totD, uint* __restrict__ totS) {
    __shared__ uint red[256];
    int t = threadIdx.x;
    bool isS = blockIdx.x >= NB;
    int b = isS ? (blockIdx.x - NB) : blockIdx.x;
    const uint* cnt = isS ? cntS : cntD;
    red[t] = cnt[b * PBLK + t];
    __syncthreads();
    for (int s = 128; s > 0; s >>= 1) { if (t < s) red[t] += red[t + s]; __syncthreads(); }
    if (t == 0) (isS ? totS : totD)[b] = red[0];
}

// ---- P2b: exclusive scan of bucket totals -> baseD/baseS (NB+1 each) ----
__global__ __launch_bounds__(256)
void p2b_scan(const uint* __restrict__ totD, const uint* __restrict__ totS,
              uint* __restrict__ baseD, uint* __restrict__ baseS) {
    __shared__ uint part[256];
    int t = threadIdx.x;
    for (int dir = 0; dir < 2; ++dir) {
        const uint* tot = dir ? totS : totD;
        uint* base = dir ? baseS : baseD;
        uint v[4]; uint s = 0;
#pragma unroll
        for (int k = 0; k < 4; ++k) { v[k] = tot[t * 4 + k]; s += v[k]; }
        part[t] = s;
        __syncthreads();
        if (t == 0) {
            uint a = 0;
            for (int k = 0; k < 256; ++k) { uint x = part[k]; part[k] = a; a += x; }
            base[NB] = a;
        }
        __syncthreads();
        uint a = part[t];
#pragma unroll
        for (int k = 0; k < 4; ++k) { base[t * 4 + k] = a; a += v[k]; }
        __syncthreads();
    }
}

// ---- P2c: per-bucket exclusive scan across partition blocks + base; grid 2*NB ----
__global__ __launch_bounds__(256)
void p2c_rowscan(const uint* __restrict__ cntD, const uint* __restrict__ cntS,
                 const uint* __restrict__ baseD, const uint* __restrict__ baseS,
                 uint* __restrict__ offD, uint* __restrict__ offS) {
    __shared__ uint row[PBLK];
    int t = threadIdx.x;
    bool isS = blockIdx.x >= NB;
    int b = isS ? (blockIdx.x - NB) : blockIdx.x;
    const uint* cnt = isS ? cntS : cntD;
    const uint* base = isS ? baseS : baseD;
    uint* off = isS ? offS : offD;
    row[t] = cnt[b * PBLK + t];
    __syncthreads();
    if (t == 0) {
        uint a = base[b];
        for (int k = 0; k < PBLK; ++k) { uint v = row[k]; row[k] = a; a += v; }
    }
    __syncthreads();
    off[b * PBLK + t] = row[t];
}

// ---- P3: reorder edges into bucket-contiguous uint2 records; 1024 threads ----
__global__ __launch_bounds__(PT)
void p3_scatter(const int* __restrict__ ei, const float* __restrict__ ew,
                const uint* __restrict__ offD, const uint* __restrict__ offS,
                uint2* __restrict__ recD, uint2* __restrict__ recS) {
    __shared__ uint curD[NB], curS[NB];
    int t = threadIdx.x, blk = blockIdx.x;
    for (int b = t; b < NB; b += PT) {
        curD[b] = offD[b * PBLK + blk];
        curS[b] = offS[b * PBLK + blk];
    }
    __syncthreads();
    int lo = blk * CHUNK, hi = min(lo + CHUNK, N_EDGES);
    for (int e = lo + t; e < hi; e += PT) {
        uint s = (uint)ei[e];
        uint d = (uint)ei[N_EDGES + e];
        uint wfix = (uint)(ew[e] * 16777216.0f + 0.5f);   // 2^24 fixed point
        uint bd = d / RNG, dl = d - bd * RNG;
        uint p = atomicAdd(&curD[bd], 1u);                // u32 LDS atomic (native)
        recD[p] = make_uint2(s | (dl << 20), (dl << 25) | wfix);
        uint bs = s / RNG, sl = s - bs * RNG;
        uint p2 = atomicAdd(&curS[bs], 1u);
        recS[p2] = make_uint2(d | (sl << 20), (sl << 25) | wfix);
    }
}

// ---- KDEG: per-bucket weighted degree via u32 fixed-point LDS atomics ----
// D-binned (own=dst) -> deg_in -> inv_in ; S-binned (own=src) -> deg_out -> inv_out
__global__ __launch_bounds__(256)
void kdeg(const uint2* __restrict__ recD, const uint2* __restrict__ recS,
          const uint* __restrict__ baseD, const uint* __restrict__ baseS,
          float* __restrict__ inv_in, float* __restrict__ inv_out) {
    __shared__ uint dacc[RNG];
    int t = threadIdx.x;
    bool isS = blockIdx.x >= NB;
    int b = isS ? (blockIdx.x - NB) : blockIdx.x;
    const uint2* rec = isS ? recS : recD;
    const uint* base = isS ? baseS : baseD;
    float* inv = isS ? inv_out : inv_in;
    for (int i = t; i < RNG; i += 256) dacc[i] = 0u;
    __syncthreads();
    uint lo = base[b], hi = base[b + 1];
    for (uint e = lo + t; e < hi; e += 256) {
        uint ry = rec[e].y;
        atomicAdd(&dacc[ry >> 25], ry & 0x1FFFFFFu);      // native u32 LDS atomic
    }
    __syncthreads();
    int n0 = b * RNG;
    for (int i = t; i < RNG; i += 256) {
        int n = n0 + i;
        if (n < N_NODES) inv[n] = 16777216.0f / (float)dacc[i];  // inf for isolated: never gathered
    }
}

// ---- P4: counting-sort bucket records by local node, register-accumulate ----
// Exact r7 structure (CAP 2560, serial scan) — the measured-fast config.
// thread (slot s = t>>4, feature f = t&15); slot s owns local nodes s, s+16, ...
__global__ __launch_bounds__(256)
void p4_sorted(const uint2* __restrict__ recD, const uint2* __restrict__ recS,
               const uint* __restrict__ baseD, const uint* __restrict__ baseS,
               const float* __restrict__ x,
               const float* __restrict__ inv_out, const float* __restrict__ inv_in,
               float* __restrict__ To, float* __restrict__ Ti) {
    __shared__ uint sorted[CAP];          // 10 KiB
    __shared__ uint scnt[RNG];
    __shared__ uint cstart[RNG + 1];
    __shared__ uint scur[RNG];
    int t = threadIdx.x;
    bool isS = blockIdx.x >= NB;
    int b = isS ? (blockIdx.x - NB) : blockIdx.x;
    const uint2* rec = isS ? recS : recD;
    const uint* base = isS ? baseS : baseD;
    const float* inv = isS ? inv_in : inv_out;
    float* out = isS ? Ti : To;

    int f = t & 15, s = t >> 4;
    uint lo = base[b], hi = base[b + 1];

    float acc[ACCN];
#pragma unroll
    for (int k = 0; k < ACCN; ++k) acc[k] = 0.0f;

    for (uint chunk = lo; chunk < hi; chunk += CAP) {
        uint n_in = min(hi - chunk, (uint)CAP);
        for (int i = t; i < RNG; i += 256) scnt[i] = 0;
        __syncthreads();
        // pass A: stream records, count by local node, stash .x in regs
        uint stash[CAPT];
#pragma unroll
        for (int k = 0; k < CAPT; ++k) {
            uint i = (uint)(k * 256 + t);
            if (i < n_in) {
                uint r = rec[chunk + i].x;
                stash[k] = r;
                atomicAdd(&scnt[r >> 20], 1u);    // u32 LDS atomic (native)
            }
        }
        __syncthreads();
        if (t == 0) {
            uint a = 0;
            for (int n = 0; n < RNG; ++n) { cstart[n] = a; a += scnt[n]; }
            cstart[RNG] = a;
        }
        __syncthreads();
        for (int i = t; i < RNG; i += 256) scur[i] = cstart[i];
        __syncthreads();
        // pass B: place into sorted order
#pragma unroll
        for (int k = 0; k < CAPT; ++k) {
            uint i = (uint)(k * 256 + t);
            if (i < n_in) {
                uint r = stash[k];
                uint p = atomicAdd(&scur[r >> 20], 1u);
                sorted[p] = r;
            }
        }
        __syncthreads();
        // accumulate: slot s walks its nodes' contiguous edge lists
#pragma unroll
        for (int k = 0; k < ACCN; ++k) {
            int n = s + 16 * k;
            if (n < RNG) {
                uint j = cstart[n], j1 = cstart[n + 1];
                for (; j + 8 <= j1; j += 8) {
                    uint p0 = sorted[j],     p1 = sorted[j + 1], p2 = sorted[j + 2], p3 = sorted[j + 3];
                    uint p4 = sorted[j + 4], p5 = sorted[j + 5], p6 = sorted[j + 6], p7 = sorted[j + 7];
                    uint o0 = p0 & 0xFFFFFu, o1 = p1 & 0xFFFFFu, o2 = p2 & 0xFFFFFu, o3 = p3 & 0xFFFFFu;
                    uint o4 = p4 & 0xFFFFFu, o5 = p5 & 0xFFFFFu, o6 = p6 & 0xFFFFFu, o7 = p7 & 0xFFFFFu;
                    float g0 = x[(size_t)o0 * NF + f], g1 = x[(size_t)o1 * NF + f];
                    float g2 = x[(size_t)o2 * NF + f], g3 = x[(size_t)o3 * NF + f];
                    float g4 = x[(size_t)o4 * NF + f], g5 = x[(size_t)o5 * NF + f];
                    float g6 = x[(size_t)o6 * NF + f], g7 = x[(size_t)o7 * NF + f];
                    float w0 = inv[o0], w1 = inv[o1], w2 = inv[o2], w3 = inv[o3];
                    float w4 = inv[o4], w5 = inv[o5], w6 = inv[o6], w7 = inv[o7];
                    acc[k] += g0 * w0 + g1 * w1 + g2 * w2 + g3 * w3
                            + g4 * w4 + g5 * w5 + g6 * w6 + g7 * w7;
                }
                for (; j < j1; ++j) {
                    uint p = sorted[j];
                    uint o = p & 0xFFFFFu;
                    acc[k] += x[(size_t)o * NF + f] * inv[o];
                }
            }
        }
        __syncthreads();   // before next chunk overwrites LDS
    }

    // write out: each (node, f) exactly once, coalesced
#pragma unroll
    for (int k = 0; k < ACCN; ++k) {
        int n = s + 16 * k;
        if (n < RNG) {
            size_t g = (size_t)b * RNG + n;
            if (g < N_NODES) out[g * NF + f] = acc[k];
        }
    }
}

// ---- combine + TRANSPOSE weights: WT[h][c] ----
__global__ void wprep_kernel(const float* __restrict__ Wz, const float* __restrict__ Wh,
                             float* __restrict__ WzT, float* __restrict__ WhT) {
    int t = blockIdx.x * blockDim.x + threadIdx.x;
    if (t >= 2 * CIN3 * HID) return;
    const float* W = (t < CIN3 * HID) ? Wz : Wh;
    float* WT      = (t < CIN3 * HID) ? WzT : WhT;
    int i = (t < CIN3 * HID) ? t : (t - CIN3 * HID);
    int c = i / HID;
    int h = i - c * HID;
    float v;
    if (c < 16)      v = W[(0 * 48 + c) * 32 + h] + W[(2 * 48 + c) * 32 + h];
    else if (c < 32) v = W[(1 * 48 + (c - 16)) * 32 + h];
    else             v = W[(3 * 48 + (c - 32)) * 32 + h];
    WT[h * CIN3 + c] = v;
}

// ---- per-node fused GRU-collapse + output ----
__global__ __launch_bounds__(256)
void node_kernel(const float* __restrict__ x, const float* __restrict__ To,
                 const float* __restrict__ Ti,
                 const float* __restrict__ WzT, const float* __restrict__ WhT,
                 const float* __restrict__ bz, const float* __restrict__ bh,
                 const float* __restrict__ linW, const float* __restrict__ linb,
                 float* __restrict__ out) {
    __shared__ __align__(16) float sWz[HID * CIN3];
    __shared__ __align__(16) float sWh[HID * CIN3];
    __shared__ __align__(16) float sBz[HID], sBh[HID];
    __shared__ __align__(16) float sLW[HID * OUTD];
    __shared__ __align__(16) float sLb[OUTD];

    for (int i = threadIdx.x; i < HID * CIN3; i += 256) { sWz[i] = WzT[i]; sWh[i] = WhT[i]; }
    if (threadIdx.x < HID) { sBz[threadIdx.x] = bz[threadIdx.x]; sBh[threadIdx.x] = bh[threadIdx.x]; }
    for (int i = threadIdx.x; i < HID * OUTD; i += 256) sLW[i] = linW[i];
    if (threadIdx.x < OUTD) sLb[threadIdx.x] = linb[threadIdx.x];
    __syncthreads();

    int n = blockIdx.x * 256 + threadIdx.x;
    if (n >= N_NODES) return;

    float feat[CIN3];
#pragma unroll
    for (int q = 0; q < 4; ++q) {
        float4 v = ((const float4*)(x + (size_t)n * NF))[q];
        feat[q*4+0]=v.x; feat[q*4+1]=v.y; feat[q*4+2]=v.z; feat[q*4+3]=v.w;
    }
#pragma unroll
    for (int q = 0; q < 4; ++q) {
        float4 v = ((const float4*)(To + (size_t)n * NF))[q];
        feat[16+q*4+0]=v.x; feat[16+q*4+1]=v.y; feat[16+q*4+2]=v.z; feat[16+q*4+3]=v.w;
    }
#pragma unroll
    for (int q = 0; q < 4; ++q) {
        float4 v = ((const float4*)(Ti + (size_t)n * NF))[q];
        feat[32+q*4+0]=v.x; feat[32+q*4+1]=v.y; feat[32+q*4+2]=v.z; feat[32+q*4+3]=v.w;
    }

    float o[OUTD];
#pragma unroll
    for (int j = 0; j < OUTD; ++j) o[j] = sLb[j];

#pragma unroll 2
    for (int h = 0; h < HID; ++h) {
        float az = sBz[h];
        float ah = sBh[h];
        const float4* wz4 = (const float4*)(sWz + h * CIN3);
        const float4* wh4 = (const float4*)(sWh + h * CIN3);
#pragma unroll
        for (int q = 0; q < CIN3 / 4; ++q) {
            float4 wz = wz4[q];
            float4 wh = wh4[q];
            float f0 = feat[q*4+0], f1 = feat[q*4+1], f2 = feat[q*4+2], f3 = feat[q*4+3];
            az += f0*wz.x + f1*wz.y + f2*wz.z + f3*wz.w;
            ah += f0*wh.x + f1*wh.y + f2*wh.z + f3*wh.w;
        }
        float z  = 1.0f / (1.0f + expf(-az));
        float ht = tanhf(ah);
        float r  = fmaxf((1.0f - z) * ht, 0.0f);
#pragma unroll
        for (int j = 0; j < OUTD; ++j) o[j] += r * sLW[h * OUTD + j];
    }

    float4* op = (float4*)(out + (size_t)n * OUTD);
    op[0] = make_float4(o[0], o[1], o[2],  o[3]);
    op[1] = make_float4(o[4], o[5], o[6],  o[7]);
    op[2] = make_float4(o[8], o[9], o[10], o[11]);
}

// ============================================================================
// FALLBACK (ws too small): compact atomic path (round-2 structure)
// ============================================================================
__global__ void zero_kernel(float* __restrict__ p, int n) {
    int i = blockIdx.x * blockDim.x + threadIdx.x;
    int stride = gridDim.x * blockDim.x;
    for (; i < n; i += stride) p[i] = 0.0f;
}
__global__ void degree_compact(const int* __restrict__ ei, const float* __restrict__ ew,
                               float* __restrict__ deg_out, float* __restrict__ deg_in) {
    int e = blockIdx.x * blockDim.x + threadIdx.x;
    if (e >= N_EDGES) return;
    atomicAdd(&deg_out[ei[e]], ew[e]);
    atomicAdd(&deg_in[ei[N_EDGES + e]], ew[e]);
}
__global__ void rcp_compact(float* __restrict__ a, float* __restrict__ b) {
    int n = blockIdx.x * blockDim.x + threadIdx.x;
    if (n >= N_NODES) return;
    a[n] = 1.0f / a[n]; b[n] = 1.0f / b[n];
}
__global__ __launch_bounds__(256)
void scatter_kernel(const int* __restrict__ ei, const float* __restrict__ x,
                    const float* __restrict__ inv_out, const float* __restrict__ inv_in,
                    float* __restrict__ To, float* __restrict__ Ti) {
    int t = blockIdx.x * blockDim.x + threadIdx.x;
    if (t >= N_EDGES * NF) return;
    int e = t >> 4, f = t & 15;
    int src = ei[e], dst = ei[N_EDGES + e];
    atomicAdd(&To[dst * NF + f], x[src * NF + f] * inv_out[src]);
    atomicAdd(&Ti[src * NF + f], x[dst * NF + f] * inv_in[dst]);
}

// ============================================================================
extern "C" void kernel_launch(void* const* d_in, const int* in_sizes, int n_in,
                              void* d_out, int out_size, void* d_ws, size_t ws_size,
                              hipStream_t stream) {
    const float* x    = (const float*)d_in[0];
    const int*   ei   = (const int*)  d_in[1];
    const float* ew   = (const float*)d_in[2];
    const float* Wz   = (const float*)d_in[3];
    const float* bz   = (const float*)d_in[4];
    // d_in[5], d_in[6] (W_r, b_r) dead: H0 == 0 makes the reset gate unused.
    const float* Wh   = (const float*)d_in[7];
    const float* bh   = (const float*)d_in[8];
    const float* linW = (const float*)d_in[9];
    const float* linb = (const float*)d_in[10];

    float* ws = (float*)d_ws;

    // ---- main-path workspace layout (dwords) ----
    size_t off = 0;
    uint2* recD = (uint2*)(ws + off); off += 2 * (size_t)N_EDGES;
    uint2* recS = (uint2*)(ws + off); off += 2 * (size_t)N_EDGES;
    uint* cntD  = (uint*)(ws + off);  off += (size_t)NB * PBLK;
    uint* cntS  = (uint*)(ws + off);  off += (size_t)NB * PBLK;
    uint* offD  = (uint*)(ws + off);  off += (size_t)NB * PBLK;
    uint* offS  = (uint*)(ws + off);  off += (size_t)NB * PBLK;
    uint* totD  = (uint*)(ws + off);  off += NB;
    uint* totS  = (uint*)(ws + off);  off += NB;
    uint* baseD = (uint*)(ws + off);  off += NB + 1;
    uint* baseS = (uint*)(ws + off);  off += NB + 1;
    float* inv_out = ws + off;        off += N_NODES;
    float* inv_in  = ws + off;        off += N_NODES;
    float* To   = ws + off;           off += (size_t)NF * N_NODES;
    float* Ti   = ws + off;           off += (size_t)NF * N_NODES;
    float* WzT  = ws + off;           off += CIN3 * HID;
    float* WhT  = ws + off;           off += CIN3 * HID;
    size_t need = off * sizeof(float);

    if (ws_size >= need) {
        p1_count    <<<PBLK,  PT,  0, stream>>>(ei, cntD, cntS);
        p2a_rowsum  <<<2*NB,  256, 0, stream>>>(cntD, cntS, totD, totS);
        p2b_scan    <<<1,     256, 0, stream>>>(totD, totS, baseD, baseS);
        p2c_rowscan <<<2*NB,  256, 0, stream>>>(cntD, cntS, baseD, baseS, offD, offS);
        p3_scatter  <<<PBLK,  PT,  0, stream>>>(ei, ew, offD, offS, recD, recS);
        kdeg        <<<2*NB,  256, 0, stream>>>(recD, recS, baseD, baseS, inv_in, inv_out);
        wprep_kernel<<<12,    256, 0, stream>>>(Wz, Wh, WzT, WhT);
        p4_sorted   <<<2*NB,  256, 0, stream>>>(recD, recS, baseD, baseS, x, inv_out, inv_in, To, Ti);
        node_kernel <<<(N_NODES + 255) / 256, 256, 0, stream>>>(x, To, Ti, WzT, WhT, bz, bh,
                                                                linW, linb, (float*)d_out);
    } else {
        float* fTo  = ws;
        float* fTi  = ws + 16 * N_NODES;
        float* fIo  = ws + 32 * N_NODES;
        float* fIi  = ws + 33 * N_NODES;
        float* fWzT = ws + 34 * N_NODES;
        float* fWhT = fWzT + CIN3 * HID;
        zero_kernel<<<2048, 256, 0, stream>>>(fTo, 34 * N_NODES);
        degree_compact<<<(N_EDGES + 255) / 256, 256, 0, stream>>>(ei, ew, fIo, fIi);
        rcp_compact<<<(N_NODES + 255) / 256, 256, 0, stream>>>(fIo, fIi);
        scatter_kernel<<<(N_EDGES * NF + 255) / 256, 256, 0, stream>>>(ei, x, fIo, fIi, fTo, fTi);
        wprep_kernel<<<12, 256, 0, stream>>>(Wz, Wh, fWzT, fWhT);
        node_kernel<<<(N_NODES + 255) / 256, 256, 0, stream>>>(x, fTo, fTi, fWzT, fWhT, bz, bh,
                                                               linW, linb, (float*)d_out);
    }
}